// Round 19
// baseline (92.036 us; speedup 1.0000x reference)
//
#include <hip/hip_runtime.h>
#include <hip/hip_bf16.h>
#include <stdint.h>

#define DENSE_D 512
#define HIDDEN1 512
#define HIDDEN2 256
#define EMB_D   64
#define NFEAT   7
#define NROWS   9
#define NPAIRS  36
#define COMB    100          // 64 + 36
#define KPROJ   128          // padded K for projection GEMM
#define PROJ    128
#define C_CAMP  1000
#define C_FEAT  316
#define NQ_FEAT 317
#define TROWS   16           // rows per tail_rest block
#define GROWS   8            // rows per gather block
#define HISTMAX 64           // LDS offset-table stride (>= max items/row)

typedef __attribute__((ext_vector_type(8)))  __bf16 bf16x8;
typedef __attribute__((ext_vector_type(8)))  unsigned short ushort8;
typedef __attribute__((ext_vector_type(4)))  float  facc4;

#define GLD_LDS16(gp, lp) __builtin_amdgcn_global_load_lds( \
    (__attribute__((address_space(1))) void*)(gp), \
    (__attribute__((address_space(3))) void*)(lp), 16, 0, 0)

__device__ inline unsigned short f2bf(float f) {
    __hip_bfloat16 h = __float2bfloat16(f);
    return *reinterpret_cast<unsigned short*>(&h);
}
__device__ inline float blo(unsigned int u) { return __uint_as_float(u << 16); }
__device__ inline float bhi(unsigned int u) { return __uint_as_float(u & 0xffff0000u); }

// ---------------------------------------------------------------------------
// bf16 MFMA GEMM, 16x16x32 frags: C = act(A @ W^T + bias), bf16 out.
// WM x WN waves; per-wave (BM/WM) x (BN/WN). LDS k-chunk-major [BK/8][R][8].
// A_F32: A fp32, cast to bf16 during reg-staging; else A bf16 via GLD16.
// ---------------------------------------------------------------------------
template<int BM, int BN, int BK, int WM, int WN, bool RELU, bool A_F32>
__global__ __launch_bounds__(WM * WN * 64)
void gemm16(const void* __restrict__ Avoid,
            const unsigned short* __restrict__ W,
            const float* __restrict__ bias,
            unsigned short* __restrict__ Cout,
            int M, int N, int K)
{
    constexpr int THREADS = WM * WN * 64;
    constexpr int MREP    = BM / (WM * 16);
    constexpr int NREP    = BN / (WN * 16);
    constexpr int SUB     = BK / 32;
    constexpr int ACH     = BM * BK / 8;
    constexpr int BCH     = BN * BK / 8;

    __shared__ __align__(16) unsigned short Asm[BK / 8][BM][8];
    __shared__ __align__(16) unsigned short Bsm[BK / 8][BN][8];

    const int tid  = threadIdx.x;
    const int lane = tid & 63;
    const int wave = tid >> 6;
    const int wm   = wave / WN;
    const int wn   = wave % WN;
    const int row0 = blockIdx.x * BM;
    const int col0 = blockIdx.y * BN;
    const int fr   = lane & 15;
    const int fk   = lane >> 4;

    facc4 acc[MREP][NREP] = {};

    for (int k0 = 0; k0 < K; k0 += BK) {
        if (A_F32) {
            const float* Af = (const float*)Avoid;
            #pragma unroll
            for (int it = 0; it < ACH / THREADS; ++it) {
                const int p  = it * THREADS + tid;
                const int r  = p & (BM - 1);
                const int kc = p / BM;
                const float* src = Af + (size_t)(row0 + r) * K + k0 + kc * 8;
                const float4 v0 = *reinterpret_cast<const float4*>(src);
                const float4 v1 = *reinterpret_cast<const float4*>(src + 4);
                ushort8 cv;
                cv[0] = f2bf(v0.x); cv[1] = f2bf(v0.y);
                cv[2] = f2bf(v0.z); cv[3] = f2bf(v0.w);
                cv[4] = f2bf(v1.x); cv[5] = f2bf(v1.y);
                cv[6] = f2bf(v1.z); cv[7] = f2bf(v1.w);
                *reinterpret_cast<ushort8*>(
                    (unsigned short*)(&Asm[0][0][0]) + (size_t)p * 8) = cv;
            }
        } else {
            const unsigned short* Ab = (const unsigned short*)Avoid;
            #pragma unroll
            for (int it = 0; it < ACH / THREADS; ++it) {
                const int p  = it * THREADS + tid;
                const int r  = p & (BM - 1);
                const int kc = p / BM;
                GLD_LDS16(Ab + (size_t)(row0 + r) * K + k0 + kc * 8,
                          (&Asm[0][0][0]) + (size_t)p * 8);
            }
        }
        #pragma unroll
        for (int it = 0; it < BCH / THREADS; ++it) {
            const int p  = it * THREADS + tid;
            const int r  = p & (BN - 1);
            const int kc = p / BN;
            GLD_LDS16(W + (size_t)(col0 + r) * K + k0 + kc * 8,
                      (&Bsm[0][0][0]) + (size_t)p * 8);
        }
        __syncthreads();

        #pragma unroll
        for (int s = 0; s < SUB; ++s) {
            bf16x8 af[MREP], bw[NREP];
            #pragma unroll
            for (int m = 0; m < MREP; ++m)
                af[m] = *reinterpret_cast<const bf16x8*>(
                    &Asm[s * 4 + fk][wm * (MREP * 16) + m * 16 + fr][0]);
            #pragma unroll
            for (int n = 0; n < NREP; ++n)
                bw[n] = *reinterpret_cast<const bf16x8*>(
                    &Bsm[s * 4 + fk][wn * (NREP * 16) + n * 16 + fr][0]);
            #pragma unroll
            for (int m = 0; m < MREP; ++m)
                #pragma unroll
                for (int n = 0; n < NREP; ++n)
                    acc[m][n] = __builtin_amdgcn_mfma_f32_16x16x32_bf16(
                        af[m], bw[n], acc[m][n], 0, 0, 0);
        }
        __syncthreads();
    }

    // C/D layout: col=lane&15, row=(lane>>4)*4+j  [m89/m91-verified]
    #pragma unroll
    for (int n = 0; n < NREP; ++n) {
        const int col = col0 + wn * (NREP * 16) + n * 16 + fr;
        const float bv = bias[col];
        #pragma unroll
        for (int m = 0; m < MREP; ++m) {
            #pragma unroll
            for (int j = 0; j < 4; ++j) {
                const int row = row0 + wm * (MREP * 16) + m * 16 + fk * 4 + j;
                float v = acc[m][n][j] + bv;
                if (RELU) v = fmaxf(v, 0.f);
                Cout[(size_t)row * N + col] = f2bf(v);
            }
        }
    }
}

// ---------------------------------------------------------------------------
// One-shot prep: cast weights/tables to bf16 (NOT x), pad Wp to [128][128].
// ---------------------------------------------------------------------------
__device__ inline void cast_seg(const float* __restrict__ src,
                                unsigned short* __restrict__ dst,
                                int n4, int id, int stride)
{
    for (int i = id; i < n4; i += stride) {
        const float4 v = reinterpret_cast<const float4*>(src)[i];
        ushort4 o;
        o.x = f2bf(v.x); o.y = f2bf(v.y); o.z = f2bf(v.z); o.w = f2bf(v.w);
        reinterpret_cast<ushort4*>(dst)[i] = o;
    }
}

__global__ __launch_bounds__(256)
void prep_all(const float* __restrict__ W0, const float* __restrict__ W1,
              const float* __restrict__ W2, const float* __restrict__ Wp,
              const float* __restrict__ Wq_c, const float* __restrict__ Wr_c,
              const float* __restrict__ Wq_f, const float* __restrict__ Wr_f,
              unsigned short* w0b, unsigned short* w1b, unsigned short* w2b,
              unsigned short* wpb, unsigned short* qcb, unsigned short* rcb,
              unsigned short* qfb, unsigned short* rfb)
{
    const int id = blockIdx.x * blockDim.x + threadIdx.x;
    const int stride = gridDim.x * blockDim.x;
    cast_seg(W0,   w0b, HIDDEN1 * DENSE_D / 4,   id, stride);
    cast_seg(W1,   w1b, HIDDEN2 * HIDDEN1 / 4,   id, stride);
    cast_seg(W2,   w2b, EMB_D * HIDDEN2 / 4,     id, stride);
    cast_seg(Wq_c, qcb, C_CAMP * EMB_D / 4,      id, stride);
    cast_seg(Wr_c, rcb, C_CAMP * EMB_D / 4,      id, stride);
    cast_seg(Wq_f, qfb, NFEAT * NQ_FEAT * EMB_D / 4, id, stride);
    cast_seg(Wr_f, rfb, NFEAT * C_FEAT * EMB_D / 4,  id, stride);
    for (int i = id; i < PROJ * KPROJ; i += stride) {
        const int r = i >> 7, c = i & 127;
        wpb[i] = (c < COMB) ? f2bf(Wp[r * COMB + c]) : (unsigned short)0;
    }
}

// ---------------------------------------------------------------------------
// hist_gather: standalone segment-mean gather, 8 rows/block, 256 threads.
// Half-wave (32 lanes) per row: 4 item-slots x 8 lanes x uint4 (8 dims).
// 4-round batching = 8 loads in flight. shfl_xor(8/16) slot-reduce.
// ---------------------------------------------------------------------------
__global__ __launch_bounds__(256)
void hist_gather(const int* __restrict__ hist_idx,
                 const int* __restrict__ hist_off,
                 const unsigned short* __restrict__ qcb,
                 const unsigned short* __restrict__ rcb,
                 unsigned short* __restrict__ hemb,
                 int B, int Mtot)
{
    const int r0 = blockIdx.x * GROWS;
    const int t  = threadIdx.x;

    __shared__ int2 soff[GROWS][HISTMAX];
    __shared__ int  scnt[GROWS];

    for (int p = t; p < GROWS * HISTMAX; p += 256) {
        const int row = p >> 6;
        const int i   = p & 63;
        const int br  = r0 + row;
        const int start = hist_off[br];
        const int end   = (br + 1 < B) ? hist_off[br + 1] : Mtot;
        const int cnt   = end - start;
        int2 o = make_int2(0, 0);
        if (i < cnt) {
            const int hi = hist_idx[start + i];
            const int q = hi / C_CAMP;
            o = make_int2(q * EMB_D, (hi - q * C_CAMP) * EMB_D);
        }
        soff[row][i] = o;
        if (i == 0) scnt[row] = cnt;
    }
    __syncthreads();

    const int lane = t & 63;
    const int wv   = t >> 6;
    const int half = lane >> 5;
    const int row  = wv * 2 + half;
    const int l5   = lane & 31;
    const int slot = l5 >> 3;
    const int d8   = l5 & 7;
    const int cnt  = scnt[row];

    const unsigned short* qb = qcb + d8 * 8;
    const unsigned short* rb = rcb + d8 * 8;

    float a[8] = {};
    #define ACC8(q, r) do { \
        a[0] += blo((q).x) * blo((r).x); a[1] += bhi((q).x) * bhi((r).x); \
        a[2] += blo((q).y) * blo((r).y); a[3] += bhi((q).y) * bhi((r).y); \
        a[4] += blo((q).z) * blo((r).z); a[5] += bhi((q).z) * bhi((r).z); \
        a[6] += blo((q).w) * blo((r).w); a[7] += bhi((q).w) * bhi((r).w); } while (0)

    const int full = cnt >> 2;
    int g = 0;
    for (; g + 4 <= full; g += 4) {
        int2 o[4];
        #pragma unroll
        for (int j = 0; j < 4; ++j) o[j] = soff[row][(g + j) * 4 + slot];
        uint4 uq[4], ur[4];
        #pragma unroll
        for (int j = 0; j < 4; ++j) {
            uq[j] = *reinterpret_cast<const uint4*>(qb + o[j].x);
            ur[j] = *reinterpret_cast<const uint4*>(rb + o[j].y);
        }
        #pragma unroll
        for (int j = 0; j < 4; ++j) ACC8(uq[j], ur[j]);
    }
    for (; g < full; ++g) {
        const int2 o = soff[row][g * 4 + slot];
        const uint4 uq = *reinterpret_cast<const uint4*>(qb + o.x);
        const uint4 ur = *reinterpret_cast<const uint4*>(rb + o.y);
        ACC8(uq, ur);
    }
    {
        const int idx = (full << 2) + slot;
        const int2 o = soff[row][idx & (HISTMAX - 1)];
        const uint4 uq = *reinterpret_cast<const uint4*>(qb + o.x);
        const uint4 ur = *reinterpret_cast<const uint4*>(rb + o.y);
        if (idx < cnt) ACC8(uq, ur);
    }
    #undef ACC8

    #pragma unroll
    for (int k = 0; k < 8; ++k) {
        a[k] += __shfl_xor(a[k], 8);
        a[k] += __shfl_xor(a[k], 16);
    }

    if (slot == 0) {
        const float inv = 1.f / (float)max(cnt, 1);
        union { unsigned short s[8]; uint4 u; } pk;
        #pragma unroll
        for (int k = 0; k < 8; ++k) pk.s[k] = f2bf(a[k] * inv);
        *reinterpret_cast<uint4*>(hemb + (size_t)(r0 + row) * EMB_D + d8 * 8) = pk.u;
    }
}

// ---------------------------------------------------------------------------
// tail_rest: 16 rows/block, 256 threads (4 waves).
//  1) GEMM2: dense = h1[16x256] @ W2^T + b2   (A/B direct global frags)
//  2) T[1] <- hemb; feature embeddings -> T[2..8]
//  3) 9x9 upper-tri interactions -> combs
//  4) proj: out = combs @ Wp^T + bp           (B direct global frags)
// ---------------------------------------------------------------------------
__global__ __launch_bounds__(256)
void tail_rest(const unsigned short* __restrict__ h1b,
               const unsigned short* __restrict__ w2b,
               const float* __restrict__ b2,
               const unsigned short* __restrict__ hemb,
               const int* __restrict__ feat_idx,
               const unsigned short* __restrict__ qfb,
               const unsigned short* __restrict__ rfb,
               const unsigned short* __restrict__ wpb,
               const float* __restrict__ bp,
               float* __restrict__ out)
{
    const int r0   = blockIdx.x * TROWS;
    const int t    = threadIdx.x;       // 256
    const int lane = t & 63;
    const int wave = t >> 6;            // 0..3
    const int fr   = lane & 15;
    const int fk   = lane >> 4;

    __shared__ __align__(16) unsigned short T[TROWS][NROWS][72];
    __shared__ __align__(16) unsigned short combs[TROWS][136];

    // ---- 1) GEMM2: 16x64, K=256; wave w -> cols w*16..w*16+15 ----
    {
        facc4 acc = {};
        const unsigned short* arow = h1b + (size_t)(r0 + fr) * HIDDEN2;
        const unsigned short* brow = w2b + (size_t)(wave * 16 + fr) * HIDDEN2;
        #pragma unroll
        for (int kw = 0; kw < 8; ++kw) {
            const bf16x8 af = *reinterpret_cast<const bf16x8*>(arow + kw * 32 + fk * 8);
            const bf16x8 bw = *reinterpret_cast<const bf16x8*>(brow + kw * 32 + fk * 8);
            acc = __builtin_amdgcn_mfma_f32_16x16x32_bf16(af, bw, acc, 0, 0, 0);
        }
        const int col = wave * 16 + fr;
        const float bv = b2[col];
        #pragma unroll
        for (int j = 0; j < 4; ++j) {
            const int row = fk * 4 + j;
            const unsigned short hv = f2bf(acc[j] + bv);
            T[row][0][col]  = hv;
            combs[row][col] = hv;
        }
    }

    // zero combs[.][100..135]
    for (int p = t; p < TROWS * 18; p += 256) {
        const int row = p / 18, c = p % 18;
        *reinterpret_cast<unsigned int*>(&combs[row][100 + c * 2]) = 0u;
    }

    // T[1] <- hemb (128 threads, uint4 = 8 dims each)
    if (t < TROWS * 8) {
        const int row = t >> 3, o8 = t & 7;
        const uint4 v = *reinterpret_cast<const uint4*>(
            hemb + (size_t)(r0 + row) * EMB_D + o8 * 8);
        *reinterpret_cast<uint4*>(&T[row][1][o8 * 8]) = v;
    }

    // ---- 2) feature embeddings: 16 threads per row, 4 dims each ----
    {
        const int row = t >> 4;          // 0..15
        const int oc  = t & 15;          // dim quad
        const int br  = r0 + row;
        const int fbase = br * NFEAT;
        #pragma unroll
        for (int f = 0; f < NFEAT; ++f) {
            const int fi = feat_idx[fbase + f];
            const int q = fi / C_FEAT, r = fi - q * C_FEAT;
            const uint2 qv = *reinterpret_cast<const uint2*>(
                qfb + ((size_t)f * NQ_FEAT + q) * EMB_D + oc * 4);
            const uint2 rv = *reinterpret_cast<const uint2*>(
                rfb + ((size_t)f * C_FEAT + r) * EMB_D + oc * 4);
            union { ushort4 v; uint2 u; } pk;
            pk.v.x = f2bf(blo(qv.x) * blo(rv.x));
            pk.v.y = f2bf(bhi(qv.x) * bhi(rv.x));
            pk.v.z = f2bf(blo(qv.y) * blo(rv.y));
            pk.v.w = f2bf(bhi(qv.y) * bhi(rv.y));
            *reinterpret_cast<uint2*>(&T[row][2 + f][oc * 4]) = pk.u;
        }
    }
    __syncthreads();

    // ---- 3) interactions: 36 pairs x 16 rows ----
    for (int p = t; p < NPAIRS * TROWS; p += 256) {
        const int row = p & (TROWS - 1);
        const int pr  = p / TROWS;
        int i = 0, rem = pr;
        while (rem >= (NROWS - 1) - i) { rem -= (NROWS - 1) - i; ++i; }
        const int j = i + 1 + rem;
        const unsigned short* ti = &T[row][i][0];
        const unsigned short* tj = &T[row][j][0];
        float s = 0.f;
        #pragma unroll
        for (int d = 0; d < EMB_D; d += 4) {
            const uint2 u = *reinterpret_cast<const uint2*>(ti + d);
            const uint2 v = *reinterpret_cast<const uint2*>(tj + d);
            s += blo(u.x) * blo(v.x) + bhi(u.x) * bhi(v.x)
               + blo(u.y) * blo(v.y) + bhi(u.y) * bhi(v.y);
        }
        combs[row][EMB_D + pr] = f2bf(s);
    }
    __syncthreads();

    // ---- 4) proj: 16x128, K=128; wave w -> cols w*32..w*32+31 ----
    {
        facc4 acc[2] = {};
        #pragma unroll
        for (int kw = 0; kw < 4; ++kw) {
            const bf16x8 af = *reinterpret_cast<const bf16x8*>(
                &combs[fr][kw * 32 + fk * 8]);
            #pragma unroll
            for (int n = 0; n < 2; ++n) {
                const bf16x8 bw = *reinterpret_cast<const bf16x8*>(
                    wpb + (size_t)(wave * 32 + n * 16 + fr) * KPROJ + kw * 32 + fk * 8);
                acc[n] = __builtin_amdgcn_mfma_f32_16x16x32_bf16(af, bw, acc[n], 0, 0, 0);
            }
        }
        #pragma unroll
        for (int n = 0; n < 2; ++n) {
            const int col = wave * 32 + n * 16 + fr;
            const float bv = bp[col];
            #pragma unroll
            for (int j = 0; j < 4; ++j) {
                const int row = fk * 4 + j;
                out[(size_t)(r0 + row) * PROJ + col] = acc[n][j] + bv;
            }
        }
    }
}

// ---------------------------------------------------------------------------
extern "C" void kernel_launch(void* const* d_in, const int* in_sizes, int n_in,
                              void* d_out, int out_size, void* d_ws, size_t ws_size,
                              hipStream_t stream)
{
    const float* x        = (const float*)d_in[0];
    const int*   hist_idx = (const int*)  d_in[1];
    const int*   hist_off = (const int*)  d_in[2];
    const int*   feat_idx = (const int*)  d_in[3];
    const float* Wq_c     = (const float*)d_in[4];
    const float* Wr_c     = (const float*)d_in[5];
    const float* Wq_f     = (const float*)d_in[6];
    const float* Wr_f     = (const float*)d_in[7];
    const float* W0       = (const float*)d_in[8];
    const float* b0       = (const float*)d_in[9];
    const float* W1       = (const float*)d_in[10];
    const float* b1       = (const float*)d_in[11];
    const float* W2       = (const float*)d_in[12];
    const float* b2       = (const float*)d_in[13];
    const float* Wp       = (const float*)d_in[14];
    const float* bp       = (const float*)d_in[15];

    const int M    = in_sizes[0] / DENSE_D;   // 16384
    const int Mtot = in_sizes[1];             // B*HIST

    char* w = (char*)d_ws;
    auto take = [&](size_t bytes) { char* p = w; w += (bytes + 255) & ~(size_t)255; return p; };
    unsigned short* w0b = (unsigned short*)take(HIDDEN1 * DENSE_D * 2);
    unsigned short* w1b = (unsigned short*)take(HIDDEN2 * HIDDEN1 * 2);
    unsigned short* w2b = (unsigned short*)take(EMB_D * HIDDEN2 * 2);
    unsigned short* wpb = (unsigned short*)take(PROJ * KPROJ * 2);
    unsigned short* qcb = (unsigned short*)take(C_CAMP * EMB_D * 2);
    unsigned short* rcb = (unsigned short*)take(C_CAMP * EMB_D * 2);
    unsigned short* qfb = (unsigned short*)take(NFEAT * NQ_FEAT * EMB_D * 2);
    unsigned short* rfb = (unsigned short*)take(NFEAT * C_FEAT * EMB_D * 2);
    unsigned short* h0b = (unsigned short*)take((size_t)M * HIDDEN1 * 2);
    unsigned short* h1b = (unsigned short*)take((size_t)M * HIDDEN2 * 2);
    unsigned short* hem = (unsigned short*)take((size_t)M * EMB_D * 2);

    prep_all<<<256, 256, 0, stream>>>(W0, W1, W2, Wp, Wq_c, Wr_c, Wq_f, Wr_f,
                                      w0b, w1b, w2b, wpb, qcb, rcb, qfb, rfb);

    // standalone gather (depends only on prep): 2048 blocks
    hist_gather<<<M / GROWS, 256, 0, stream>>>(
        hist_idx, hist_off, qcb, rcb, hem, M, Mtot);

    // layer 0: 64x128 tile, BK=64, 2x2 waves, fused fp32->bf16 A staging.
    // grid (256,4) = 1024 blocks = 4 blocks/CU (vs r12's 2) — isolates the
    // occupancy lever of the 2-phase structure (m114 implicit overlap).
    gemm16<64, 128, 64, 2, 2, true, true>
        <<<dim3(M / 64, HIDDEN1 / 128), 256, 0, stream>>>(
        x, w0b, b0, h0b, M, HIDDEN1, DENSE_D);

    // layer 1: 64x128, BK=64, 1x4 waves, A bf16 GLD.
    gemm16<64, 128, 64, 1, 4, true, false>
        <<<dim3(M / 64, HIDDEN2 / 128), 256, 0, stream>>>(
        h0b, w1b, b1, h1b, M, HIDDEN2, HIDDEN1);

    // tail_rest: 1024 blocks x 16 rows
    tail_rest<<<M / TROWS, 256, 0, stream>>>(
        h1b, w2b, b2, hem, feat_idx, qfb, rfb, wpb, bp, (float*)d_out);
}

// Round 20
// 82.275 us; speedup vs baseline: 1.1186x; 1.1186x over previous
//
#include <hip/hip_runtime.h>
#include <hip/hip_bf16.h>
#include <stdint.h>

#define DENSE_D 512
#define HIDDEN1 512
#define HIDDEN2 256
#define EMB_D   64
#define NFEAT   7
#define NROWS   9
#define NPAIRS  36
#define COMB    100          // 64 + 36
#define KPROJ   128          // padded K for projection GEMM
#define PROJ    128
#define C_CAMP  1000
#define C_FEAT  316
#define NQ_FEAT 317
#define TROWS   16           // rows per tail_rest block
#define GROWS   8            // rows per gather block
#define HISTMAX 64           // LDS offset-table stride (>= max items/row)

typedef __attribute__((ext_vector_type(8)))  __bf16 bf16x8;
typedef __attribute__((ext_vector_type(8)))  unsigned short ushort8;
typedef __attribute__((ext_vector_type(4)))  float  facc4;

#define GLD_LDS16(gp, lp) __builtin_amdgcn_global_load_lds( \
    (__attribute__((address_space(1))) void*)(gp), \
    (__attribute__((address_space(3))) void*)(lp), 16, 0, 0)

__device__ inline unsigned short f2bf(float f) {
    __hip_bfloat16 h = __float2bfloat16(f);
    return *reinterpret_cast<unsigned short*>(&h);
}
__device__ inline float blo(unsigned int u) { return __uint_as_float(u << 16); }
__device__ inline float bhi(unsigned int u) { return __uint_as_float(u & 0xffff0000u); }

// ---------------------------------------------------------------------------
// bf16 MFMA GEMM, 16x16x32 frags: C = act(A @ W^T + bias), bf16 out.
// WM x WN waves; per-wave (BM/WM) x (BN/WN). LDS k-chunk-major [BK/8][R][8].
// A_F32: A fp32, cast to bf16 during reg-staging; else A bf16 via GLD16.
// ---------------------------------------------------------------------------
template<int BM, int BN, int BK, int WM, int WN, bool RELU, bool A_F32>
__global__ __launch_bounds__(WM * WN * 64)
void gemm16(const void* __restrict__ Avoid,
            const unsigned short* __restrict__ W,
            const float* __restrict__ bias,
            unsigned short* __restrict__ Cout,
            int M, int N, int K)
{
    constexpr int THREADS = WM * WN * 64;
    constexpr int MREP    = BM / (WM * 16);
    constexpr int NREP    = BN / (WN * 16);
    constexpr int SUB     = BK / 32;
    constexpr int ACH     = BM * BK / 8;
    constexpr int BCH     = BN * BK / 8;

    __shared__ __align__(16) unsigned short Asm[BK / 8][BM][8];
    __shared__ __align__(16) unsigned short Bsm[BK / 8][BN][8];

    const int tid  = threadIdx.x;
    const int lane = tid & 63;
    const int wave = tid >> 6;
    const int wm   = wave / WN;
    const int wn   = wave % WN;
    const int row0 = blockIdx.x * BM;
    const int col0 = blockIdx.y * BN;
    const int fr   = lane & 15;
    const int fk   = lane >> 4;

    facc4 acc[MREP][NREP] = {};

    for (int k0 = 0; k0 < K; k0 += BK) {
        if (A_F32) {
            const float* Af = (const float*)Avoid;
            #pragma unroll
            for (int it = 0; it < ACH / THREADS; ++it) {
                const int p  = it * THREADS + tid;
                const int r  = p & (BM - 1);
                const int kc = p / BM;
                const float* src = Af + (size_t)(row0 + r) * K + k0 + kc * 8;
                const float4 v0 = *reinterpret_cast<const float4*>(src);
                const float4 v1 = *reinterpret_cast<const float4*>(src + 4);
                ushort8 cv;
                cv[0] = f2bf(v0.x); cv[1] = f2bf(v0.y);
                cv[2] = f2bf(v0.z); cv[3] = f2bf(v0.w);
                cv[4] = f2bf(v1.x); cv[5] = f2bf(v1.y);
                cv[6] = f2bf(v1.z); cv[7] = f2bf(v1.w);
                *reinterpret_cast<ushort8*>(
                    (unsigned short*)(&Asm[0][0][0]) + (size_t)p * 8) = cv;
            }
        } else {
            const unsigned short* Ab = (const unsigned short*)Avoid;
            #pragma unroll
            for (int it = 0; it < ACH / THREADS; ++it) {
                const int p  = it * THREADS + tid;
                const int r  = p & (BM - 1);
                const int kc = p / BM;
                GLD_LDS16(Ab + (size_t)(row0 + r) * K + k0 + kc * 8,
                          (&Asm[0][0][0]) + (size_t)p * 8);
            }
        }
        #pragma unroll
        for (int it = 0; it < BCH / THREADS; ++it) {
            const int p  = it * THREADS + tid;
            const int r  = p & (BN - 1);
            const int kc = p / BN;
            GLD_LDS16(W + (size_t)(col0 + r) * K + k0 + kc * 8,
                      (&Bsm[0][0][0]) + (size_t)p * 8);
        }
        __syncthreads();

        #pragma unroll
        for (int s = 0; s < SUB; ++s) {
            bf16x8 af[MREP], bw[NREP];
            #pragma unroll
            for (int m = 0; m < MREP; ++m)
                af[m] = *reinterpret_cast<const bf16x8*>(
                    &Asm[s * 4 + fk][wm * (MREP * 16) + m * 16 + fr][0]);
            #pragma unroll
            for (int n = 0; n < NREP; ++n)
                bw[n] = *reinterpret_cast<const bf16x8*>(
                    &Bsm[s * 4 + fk][wn * (NREP * 16) + n * 16 + fr][0]);
            #pragma unroll
            for (int m = 0; m < MREP; ++m)
                #pragma unroll
                for (int n = 0; n < NREP; ++n)
                    acc[m][n] = __builtin_amdgcn_mfma_f32_16x16x32_bf16(
                        af[m], bw[n], acc[m][n], 0, 0, 0);
        }
        __syncthreads();
    }

    // C/D layout: col=lane&15, row=(lane>>4)*4+j  [m89/m91-verified]
    #pragma unroll
    for (int n = 0; n < NREP; ++n) {
        const int col = col0 + wn * (NREP * 16) + n * 16 + fr;
        const float bv = bias[col];
        #pragma unroll
        for (int m = 0; m < MREP; ++m) {
            #pragma unroll
            for (int j = 0; j < 4; ++j) {
                const int row = row0 + wm * (MREP * 16) + m * 16 + fk * 4 + j;
                float v = acc[m][n][j] + bv;
                if (RELU) v = fmaxf(v, 0.f);
                Cout[(size_t)row * N + col] = f2bf(v);
            }
        }
    }
}

// ---------------------------------------------------------------------------
// One-shot prep: cast weights/tables to bf16 (NOT x), pad Wp to [128][128].
// ---------------------------------------------------------------------------
__device__ inline void cast_seg(const float* __restrict__ src,
                                unsigned short* __restrict__ dst,
                                int n4, int id, int stride)
{
    for (int i = id; i < n4; i += stride) {
        const float4 v = reinterpret_cast<const float4*>(src)[i];
        ushort4 o;
        o.x = f2bf(v.x); o.y = f2bf(v.y); o.z = f2bf(v.z); o.w = f2bf(v.w);
        reinterpret_cast<ushort4*>(dst)[i] = o;
    }
}

__global__ __launch_bounds__(256)
void prep_all(const float* __restrict__ W0, const float* __restrict__ W1,
              const float* __restrict__ W2, const float* __restrict__ Wp,
              const float* __restrict__ Wq_c, const float* __restrict__ Wr_c,
              const float* __restrict__ Wq_f, const float* __restrict__ Wr_f,
              unsigned short* w0b, unsigned short* w1b, unsigned short* w2b,
              unsigned short* wpb, unsigned short* qcb, unsigned short* rcb,
              unsigned short* qfb, unsigned short* rfb)
{
    const int id = blockIdx.x * blockDim.x + threadIdx.x;
    const int stride = gridDim.x * blockDim.x;
    cast_seg(W0,   w0b, HIDDEN1 * DENSE_D / 4,   id, stride);
    cast_seg(W1,   w1b, HIDDEN2 * HIDDEN1 / 4,   id, stride);
    cast_seg(W2,   w2b, EMB_D * HIDDEN2 / 4,     id, stride);
    cast_seg(Wq_c, qcb, C_CAMP * EMB_D / 4,      id, stride);
    cast_seg(Wr_c, rcb, C_CAMP * EMB_D / 4,      id, stride);
    cast_seg(Wq_f, qfb, NFEAT * NQ_FEAT * EMB_D / 4, id, stride);
    cast_seg(Wr_f, rfb, NFEAT * C_FEAT * EMB_D / 4,  id, stride);
    for (int i = id; i < PROJ * KPROJ; i += stride) {
        const int r = i >> 7, c = i & 127;
        wpb[i] = (c < COMB) ? f2bf(Wp[r * COMB + c]) : (unsigned short)0;
    }
}

// ---------------------------------------------------------------------------
// hist_gather: standalone segment-mean gather, 8 rows/block, 256 threads.
// Half-wave (32 lanes) per row: 4 item-slots x 8 lanes x uint4 (8 dims).
// 4-round batching = 8 loads in flight. shfl_xor(8/16) slot-reduce.
// ---------------------------------------------------------------------------
__global__ __launch_bounds__(256)
void hist_gather(const int* __restrict__ hist_idx,
                 const int* __restrict__ hist_off,
                 const unsigned short* __restrict__ qcb,
                 const unsigned short* __restrict__ rcb,
                 unsigned short* __restrict__ hemb,
                 int B, int Mtot)
{
    const int r0 = blockIdx.x * GROWS;
    const int t  = threadIdx.x;

    __shared__ int2 soff[GROWS][HISTMAX];
    __shared__ int  scnt[GROWS];

    for (int p = t; p < GROWS * HISTMAX; p += 256) {
        const int row = p >> 6;
        const int i   = p & 63;
        const int br  = r0 + row;
        const int start = hist_off[br];
        const int end   = (br + 1 < B) ? hist_off[br + 1] : Mtot;
        const int cnt   = end - start;
        int2 o = make_int2(0, 0);
        if (i < cnt) {
            const int hi = hist_idx[start + i];
            const int q = hi / C_CAMP;
            o = make_int2(q * EMB_D, (hi - q * C_CAMP) * EMB_D);
        }
        soff[row][i] = o;
        if (i == 0) scnt[row] = cnt;
    }
    __syncthreads();

    const int lane = t & 63;
    const int wv   = t >> 6;
    const int half = lane >> 5;
    const int row  = wv * 2 + half;
    const int l5   = lane & 31;
    const int slot = l5 >> 3;
    const int d8   = l5 & 7;
    const int cnt  = scnt[row];

    const unsigned short* qb = qcb + d8 * 8;
    const unsigned short* rb = rcb + d8 * 8;

    float a[8] = {};
    #define ACC8(q, r) do { \
        a[0] += blo((q).x) * blo((r).x); a[1] += bhi((q).x) * bhi((r).x); \
        a[2] += blo((q).y) * blo((r).y); a[3] += bhi((q).y) * bhi((r).y); \
        a[4] += blo((q).z) * blo((r).z); a[5] += bhi((q).z) * bhi((r).z); \
        a[6] += blo((q).w) * blo((r).w); a[7] += bhi((q).w) * bhi((r).w); } while (0)

    const int full = cnt >> 2;
    int g = 0;
    for (; g + 4 <= full; g += 4) {
        int2 o[4];
        #pragma unroll
        for (int j = 0; j < 4; ++j) o[j] = soff[row][(g + j) * 4 + slot];
        uint4 uq[4], ur[4];
        #pragma unroll
        for (int j = 0; j < 4; ++j) {
            uq[j] = *reinterpret_cast<const uint4*>(qb + o[j].x);
            ur[j] = *reinterpret_cast<const uint4*>(rb + o[j].y);
        }
        #pragma unroll
        for (int j = 0; j < 4; ++j) ACC8(uq[j], ur[j]);
    }
    for (; g < full; ++g) {
        const int2 o = soff[row][g * 4 + slot];
        const uint4 uq = *reinterpret_cast<const uint4*>(qb + o.x);
        const uint4 ur = *reinterpret_cast<const uint4*>(rb + o.y);
        ACC8(uq, ur);
    }
    {
        const int idx = (full << 2) + slot;
        const int2 o = soff[row][idx & (HISTMAX - 1)];
        const uint4 uq = *reinterpret_cast<const uint4*>(qb + o.x);
        const uint4 ur = *reinterpret_cast<const uint4*>(rb + o.y);
        if (idx < cnt) ACC8(uq, ur);
    }
    #undef ACC8

    #pragma unroll
    for (int k = 0; k < 8; ++k) {
        a[k] += __shfl_xor(a[k], 8);
        a[k] += __shfl_xor(a[k], 16);
    }

    if (slot == 0) {
        const float inv = 1.f / (float)max(cnt, 1);
        union { unsigned short s[8]; uint4 u; } pk;
        #pragma unroll
        for (int k = 0; k < 8; ++k) pk.s[k] = f2bf(a[k] * inv);
        *reinterpret_cast<uint4*>(hemb + (size_t)(r0 + row) * EMB_D + d8 * 8) = pk.u;
    }
}

// ---------------------------------------------------------------------------
// tail_rest: 16 rows/block, 256 threads (4 waves).
//  1) GEMM2: dense = h1[16x256] @ W2^T + b2   (A/B direct global frags)
//  2) T[1] <- hemb; feature embeddings -> T[2..8]
//  3) 9x9 upper-tri interactions -> combs
//  4) proj: out = combs @ Wp^T + bp           (B direct global frags)
// ---------------------------------------------------------------------------
__global__ __launch_bounds__(256)
void tail_rest(const unsigned short* __restrict__ h1b,
               const unsigned short* __restrict__ w2b,
               const float* __restrict__ b2,
               const unsigned short* __restrict__ hemb,
               const int* __restrict__ feat_idx,
               const unsigned short* __restrict__ qfb,
               const unsigned short* __restrict__ rfb,
               const unsigned short* __restrict__ wpb,
               const float* __restrict__ bp,
               float* __restrict__ out)
{
    const int r0   = blockIdx.x * TROWS;
    const int t    = threadIdx.x;       // 256
    const int lane = t & 63;
    const int wave = t >> 6;            // 0..3
    const int fr   = lane & 15;
    const int fk   = lane >> 4;

    __shared__ __align__(16) unsigned short T[TROWS][NROWS][72];
    __shared__ __align__(16) unsigned short combs[TROWS][136];

    // ---- 1) GEMM2: 16x64, K=256; wave w -> cols w*16..w*16+15 ----
    {
        facc4 acc = {};
        const unsigned short* arow = h1b + (size_t)(r0 + fr) * HIDDEN2;
        const unsigned short* brow = w2b + (size_t)(wave * 16 + fr) * HIDDEN2;
        #pragma unroll
        for (int kw = 0; kw < 8; ++kw) {
            const bf16x8 af = *reinterpret_cast<const bf16x8*>(arow + kw * 32 + fk * 8);
            const bf16x8 bw = *reinterpret_cast<const bf16x8*>(brow + kw * 32 + fk * 8);
            acc = __builtin_amdgcn_mfma_f32_16x16x32_bf16(af, bw, acc, 0, 0, 0);
        }
        const int col = wave * 16 + fr;
        const float bv = b2[col];
        #pragma unroll
        for (int j = 0; j < 4; ++j) {
            const int row = fk * 4 + j;
            const unsigned short hv = f2bf(acc[j] + bv);
            T[row][0][col]  = hv;
            combs[row][col] = hv;
        }
    }

    // zero combs[.][100..135]
    for (int p = t; p < TROWS * 18; p += 256) {
        const int row = p / 18, c = p % 18;
        *reinterpret_cast<unsigned int*>(&combs[row][100 + c * 2]) = 0u;
    }

    // T[1] <- hemb (128 threads, uint4 = 8 dims each)
    if (t < TROWS * 8) {
        const int row = t >> 3, o8 = t & 7;
        const uint4 v = *reinterpret_cast<const uint4*>(
            hemb + (size_t)(r0 + row) * EMB_D + o8 * 8);
        *reinterpret_cast<uint4*>(&T[row][1][o8 * 8]) = v;
    }

    // ---- 2) feature embeddings: 16 threads per row, 4 dims each ----
    {
        const int row = t >> 4;          // 0..15
        const int oc  = t & 15;          // dim quad
        const int br  = r0 + row;
        const int fbase = br * NFEAT;
        #pragma unroll
        for (int f = 0; f < NFEAT; ++f) {
            const int fi = feat_idx[fbase + f];
            const int q = fi / C_FEAT, r = fi - q * C_FEAT;
            const uint2 qv = *reinterpret_cast<const uint2*>(
                qfb + ((size_t)f * NQ_FEAT + q) * EMB_D + oc * 4);
            const uint2 rv = *reinterpret_cast<const uint2*>(
                rfb + ((size_t)f * C_FEAT + r) * EMB_D + oc * 4);
            union { ushort4 v; uint2 u; } pk;
            pk.v.x = f2bf(blo(qv.x) * blo(rv.x));
            pk.v.y = f2bf(bhi(qv.x) * bhi(rv.x));
            pk.v.z = f2bf(blo(qv.y) * blo(rv.y));
            pk.v.w = f2bf(bhi(qv.y) * bhi(rv.y));
            *reinterpret_cast<uint2*>(&T[row][2 + f][oc * 4]) = pk.u;
        }
    }
    __syncthreads();

    // ---- 3) interactions: 36 pairs x 16 rows ----
    for (int p = t; p < NPAIRS * TROWS; p += 256) {
        const int row = p & (TROWS - 1);
        const int pr  = p / TROWS;
        int i = 0, rem = pr;
        while (rem >= (NROWS - 1) - i) { rem -= (NROWS - 1) - i; ++i; }
        const int j = i + 1 + rem;
        const unsigned short* ti = &T[row][i][0];
        const unsigned short* tj = &T[row][j][0];
        float s = 0.f;
        #pragma unroll
        for (int d = 0; d < EMB_D; d += 4) {
            const uint2 u = *reinterpret_cast<const uint2*>(ti + d);
            const uint2 v = *reinterpret_cast<const uint2*>(tj + d);
            s += blo(u.x) * blo(v.x) + bhi(u.x) * bhi(v.x)
               + blo(u.y) * blo(v.y) + bhi(u.y) * bhi(v.y);
        }
        combs[row][EMB_D + pr] = f2bf(s);
    }
    __syncthreads();

    // ---- 4) proj: 16x128, K=128; wave w -> cols w*32..w*32+31 ----
    {
        facc4 acc[2] = {};
        #pragma unroll
        for (int kw = 0; kw < 4; ++kw) {
            const bf16x8 af = *reinterpret_cast<const bf16x8*>(
                &combs[fr][kw * 32 + fk * 8]);
            #pragma unroll
            for (int n = 0; n < 2; ++n) {
                const bf16x8 bw = *reinterpret_cast<const bf16x8*>(
                    wpb + (size_t)(wave * 32 + n * 16 + fr) * KPROJ + kw * 32 + fk * 8);
                acc[n] = __builtin_amdgcn_mfma_f32_16x16x32_bf16(af, bw, acc[n], 0, 0, 0);
            }
        }
        #pragma unroll
        for (int n = 0; n < 2; ++n) {
            const int col = wave * 32 + n * 16 + fr;
            const float bv = bp[col];
            #pragma unroll
            for (int j = 0; j < 4; ++j) {
                const int row = fk * 4 + j;
                out[(size_t)(r0 + row) * PROJ + col] = acc[n][j] + bv;
            }
        }
    }
}

// ---------------------------------------------------------------------------
extern "C" void kernel_launch(void* const* d_in, const int* in_sizes, int n_in,
                              void* d_out, int out_size, void* d_ws, size_t ws_size,
                              hipStream_t stream)
{
    const float* x        = (const float*)d_in[0];
    const int*   hist_idx = (const int*)  d_in[1];
    const int*   hist_off = (const int*)  d_in[2];
    const int*   feat_idx = (const int*)  d_in[3];
    const float* Wq_c     = (const float*)d_in[4];
    const float* Wr_c     = (const float*)d_in[5];
    const float* Wq_f     = (const float*)d_in[6];
    const float* Wr_f     = (const float*)d_in[7];
    const float* W0       = (const float*)d_in[8];
    const float* b0       = (const float*)d_in[9];
    const float* W1       = (const float*)d_in[10];
    const float* b1       = (const float*)d_in[11];
    const float* W2       = (const float*)d_in[12];
    const float* b2       = (const float*)d_in[13];
    const float* Wp       = (const float*)d_in[14];
    const float* bp       = (const float*)d_in[15];

    const int M    = in_sizes[0] / DENSE_D;   // 16384
    const int Mtot = in_sizes[1];             // B*HIST

    char* w = (char*)d_ws;
    auto take = [&](size_t bytes) { char* p = w; w += (bytes + 255) & ~(size_t)255; return p; };
    unsigned short* w0b = (unsigned short*)take(HIDDEN1 * DENSE_D * 2);
    unsigned short* w1b = (unsigned short*)take(HIDDEN2 * HIDDEN1 * 2);
    unsigned short* w2b = (unsigned short*)take(EMB_D * HIDDEN2 * 2);
    unsigned short* wpb = (unsigned short*)take(PROJ * KPROJ * 2);
    unsigned short* qcb = (unsigned short*)take(C_CAMP * EMB_D * 2);
    unsigned short* rcb = (unsigned short*)take(C_CAMP * EMB_D * 2);
    unsigned short* qfb = (unsigned short*)take(NFEAT * NQ_FEAT * EMB_D * 2);
    unsigned short* rfb = (unsigned short*)take(NFEAT * C_FEAT * EMB_D * 2);
    unsigned short* h0b = (unsigned short*)take((size_t)M * HIDDEN1 * 2);
    unsigned short* h1b = (unsigned short*)take((size_t)M * HIDDEN2 * 2);
    unsigned short* hem = (unsigned short*)take((size_t)M * EMB_D * 2);

    prep_all<<<256, 256, 0, stream>>>(W0, W1, W2, Wp, Wq_c, Wr_c, Wq_f, Wr_f,
                                      w0b, w1b, w2b, wpb, qcb, rcb, qfb, rfb);

    // standalone gather (depends only on prep): 2048 blocks
    hist_gather<<<M / GROWS, 256, 0, stream>>>(
        hist_idx, hist_off, qcb, rcb, hem, M, Mtot);

    // layer 0: m97 shape 128x128, BK=32, 2x2 waves, fused fp32->bf16 A staging.
    gemm16<128, 128, 32, 2, 2, true, true>
        <<<dim3(M / 128, HIDDEN1 / 128), 256, 0, stream>>>(
        x, w0b, b0, h0b, M, HIDDEN1, DENSE_D);

    // layer 1: 64x128, BK=64, 1x4 waves, A bf16 GLD.
    gemm16<64, 128, 64, 1, 4, true, false>
        <<<dim3(M / 64, HIDDEN2 / 128), 256, 0, stream>>>(
        h0b, w1b, b1, h1b, M, HIDDEN2, HIDDEN1);

    // tail_rest: 1024 blocks x 16 rows
    tail_rest<<<M / TROWS, 256, 0, stream>>>(
        h1b, w2b, b2, hem, feat_idx, qfb, rfb, wpb, bp, (float*)d_out);
}